// Round 3
// baseline (218.875 us; speedup 1.0000x reference)
//
#include <hip/hip_runtime.h>

typedef unsigned short u16;
typedef unsigned int u32;
typedef __attribute__((ext_vector_type(8))) short short8;
typedef __attribute__((ext_vector_type(4))) float f32x4;

#define NB 2
#define NSEQ 2048
#define DIM 768
#define NH 12
#define HDIM 64

#define LOG2E 1.44269504088896f
#define CFOLD 0.18033688f /* 0.125 * log2(e) */

#if defined(__has_builtin)
#if __has_builtin(__builtin_amdgcn_exp2f)
#define EXPB(x) __builtin_amdgcn_exp2f(x)
#else
#define EXPB(x) exp2f(x)
#endif
#if __has_builtin(__builtin_amdgcn_rcpf)
#define RCP(x) __builtin_amdgcn_rcpf(x)
#else
#define RCP(x) (1.0f / (x))
#endif
#else
#define EXPB(x) exp2f(x)
#define RCP(x) (1.0f / (x))
#endif

__device__ __forceinline__ u16 f2bf(float x) {
    union { float f; unsigned u; } v; v.f = x;
    unsigned r = v.u + 0x7fffu + ((v.u >> 16) & 1u);
    return (u16)(r >> 16);
}

__device__ __forceinline__ u32 pack_bf16(float a, float b) {
    union { float f; u32 u; } A, B; A.f = a; B.f = b;
    u32 ra = A.u + 0x7fffu + ((A.u >> 16) & 1u);
    u32 rb = B.u + 0x7fffu + ((B.u >> 16) & 1u);
    return __builtin_amdgcn_perm(rb, ra, 0x07060302u);
}

__device__ __forceinline__ f32x4 mfma16(short8 a, short8 b, f32x4 c) {
    return __builtin_amdgcn_mfma_f32_16x16x32_bf16(a, b, c, 0, 0, 0);
}

__device__ __forceinline__ void glds16(const u16* g, u16* l) {
    __builtin_amdgcn_global_load_lds((const __attribute__((address_space(1))) u32*)g,
                                     (__attribute__((address_space(3))) u32*)l, 16, 0, 0);
}

// ---------------- fused prep: x->bf16 cast + both weight transposes ----------------
__global__ __launch_bounds__(256) void prep(const float* __restrict__ x, u16* __restrict__ xb,
                                            const float* __restrict__ qkv_w, u16* __restrict__ wq,
                                            const float* __restrict__ proj_w, u16* __restrict__ wp) {
    const int t = threadIdx.x;
    int bid = blockIdx.x;
    if (bid < 3072) {
        int i = (bid * 256 + t) * 4;
        float4 v = *(const float4*)(x + i);
        *(uint2*)(xb + i) = make_uint2(pack_bf16(v.x, v.y), pack_bf16(v.z, v.w));
        return;
    }
    const float* in; u16* outp; int rows, cols, bx, by;
    if (bid < 3072 + 1728) {
        bid -= 3072; in = qkv_w; outp = wq; rows = 768; cols = 2304;
        bx = bid % 72; by = bid / 72;
    } else {
        bid -= 4800; in = proj_w; outp = wp; rows = 768; cols = 768;
        bx = bid % 24; by = bid / 24;
    }
    __shared__ float tile[32][33];
    int c0 = bx * 32, r0 = by * 32;
    int tx = t & 31, ty = t >> 5;
    #pragma unroll
    for (int i = 0; i < 32; i += 8)
        tile[ty + i][tx] = in[(size_t)(r0 + ty + i) * cols + c0 + tx];
    __syncthreads();
    #pragma unroll
    for (int i = 0; i < 32; i += 8)
        outp[(size_t)(c0 + ty + i) * rows + r0 + tx] = f2bf(tile[tx][ty + i]);
}

// V [bh][n][64] -> V^T [bh][64][n]
__global__ __launch_bounds__(256) void vtrans(const u16* __restrict__ vin,
                                              u16* __restrict__ vout) {
    __shared__ __align__(16) u16 tile[64][72];
    const int bh = blockIdx.y;
    const int n0 = blockIdx.x * 64;
    const int t = threadIdx.x;
    const size_t base = (size_t)bh * NSEQ * HDIM;
    int r = t >> 3, cb = (t & 7) * 8;
    *(uint4*)&tile[r][cb]      = *(const uint4*)&vin[base + (size_t)(n0 + r) * HDIM + cb];
    *(uint4*)&tile[r + 32][cb] = *(const uint4*)&vin[base + (size_t)(n0 + r + 32) * HDIM + cb];
    __syncthreads();
    #pragma unroll
    for (int half = 0; half < 2; half++) {
        int d = (t >> 3) + half * 32;
        int nb = (t & 7) * 8;
        short8 v;
        #pragma unroll
        for (int j = 0; j < 8; j++) v[j] = (short)tile[nb + j][d];
        *(short8*)&vout[base + (size_t)d * NSEQ + n0 + nb] = v;
    }
}

// ---------------- QKV GEMM ----------------
__global__ __launch_bounds__(256) void gemm_qkv(const u16* __restrict__ A,
                                                const u16* __restrict__ BT,
                                                const float* __restrict__ bias,
                                                u16* __restrict__ qo,
                                                u16* __restrict__ ko,
                                                u16* __restrict__ vo) {
    __shared__ __align__(16) u16 As[128 * 32];
    __shared__ __align__(16) u16 Bs[128 * 32];
    const int bm = blockIdx.y * 128, bn = blockIdx.x * 128;
    const int t = threadIdx.x;
    const int lane = t & 63, wave = t >> 6;
    const int l15 = lane & 15, quad = lane >> 4;
    const int wm = (wave >> 1) * 64, wn = (wave & 1) * 64;

    const u16* ga = A + (size_t)(bm + (t >> 2)) * DIM + (t & 3) * 8;
    const u16* gb = BT + (size_t)(bn + (t >> 2)) * DIM + (t & 3) * 8;
    u16* la = As + wave * 512;
    u16* lb = Bs + wave * 512;

    f32x4 acc[4][4] = {};
    for (int k0 = 0; k0 < DIM; k0 += 32) {
        __syncthreads();
        glds16(ga, la);
        glds16(ga + (size_t)64 * DIM, la + 2048);
        glds16(gb, lb);
        glds16(gb + (size_t)64 * DIM, lb + 2048);
        ga += 32; gb += 32;
        __syncthreads();
        short8 af[4], bf[4];
        #pragma unroll
        for (int i = 0; i < 4; i++) af[i] = *(const short8*)&As[(wm + i * 16 + l15) * 32 + quad * 8];
        #pragma unroll
        for (int j = 0; j < 4; j++) bf[j] = *(const short8*)&Bs[(wn + j * 16 + l15) * 32 + quad * 8];
        #pragma unroll
        for (int i = 0; i < 4; i++)
            #pragma unroll
            for (int j = 0; j < 4; j++)
                acc[i][j] = mfma16(af[i], bf[j], acc[i][j]);
    }

    #pragma unroll
    for (int i = 0; i < 4; i++) {
        int mr = bm + wm + i * 16 + quad * 4;
        int b = mr >> 11, nn = mr & 2047;
        #pragma unroll
        for (int j = 0; j < 4; j++) {
            int ncol = bn + wn + j * 16 + l15;
            int w = ncol / DIM, rem = ncol - w * DIM;
            int h = rem >> 6, hd = rem & 63;
            u16* dst = (w == 0) ? qo : (w == 1) ? ko : vo;
            float bb = bias[ncol];
            size_t idx = (((size_t)(b * NH + h)) * NSEQ + nn) * HDIM + hd;
            #pragma unroll
            for (int r = 0; r < 4; r++)
                dst[idx + (size_t)r * HDIM] = f2bf(acc[i][j][r] + bb);
        }
    }
}

// ---------------- fused region-gated attention ----------------
// block = 2 waves (128 thr), 64 q rows (32 per wave, two 16-row groups); grid (32, 24)
__global__ __launch_bounds__(128) void attn_kernel(const u16* __restrict__ Q,
                                                   const u16* __restrict__ Kg,
                                                   const u16* __restrict__ Vt,
                                                   const float* __restrict__ masks,
                                                   const float* __restrict__ lambda_r,
                                                   const float* __restrict__ theta_r,
                                                   const float* __restrict__ mask_w,
                                                   u16* __restrict__ AO) {
    const int bh = blockIdx.y;
    const int b = bh / NH, h = bh % NH;
    const int qb = blockIdx.x * 64;
    const int t = threadIdx.x, wave = t >> 6, lane = t & 63;
    const int l15 = lane & 15, quad = lane >> 4;

    __shared__ __align__(16) u16 Ks[64 * 64];      // [key][d], XOR-swizzled 16B chunks
    __shared__ __align__(16) u16 Vs[64 * 64];      // [d][key], XOR-swizzled 16B chunks
    __shared__ __align__(16) u16 Ps[2][2304];      // per-wave P, 2 groups x 16 rows x 72
    __shared__ __align__(16) float mks[64];

    const float lam = lambda_r[bh], th = theta_r[bh], mw = mask_w[bh];
    const float Bfac = lam * th * LOG2E;

    const size_t base = (size_t)bh * (NSEQ * HDIM);
    const int qrow = qb + wave * 32;

    // Q fragments (B operand: n=q, k=d), two 16-row groups
    short8 bq[2][2];
    float Afac[2], lsum[2];
    #pragma unroll
    for (int g = 0; g < 2; g++) {
        const u16* Qr = Q + base + (size_t)(qrow + g * 16 + l15) * HDIM;
        bq[g][0] = *(const short8*)(Qr + quad * 8);
        bq[g][1] = *(const short8*)(Qr + 32 + quad * 8);
        float mq = masks[bh * NSEQ + qrow + g * 16 + l15];
        Afac[g] = -lam * LOG2E * mq;
        lsum[g] = 0.f;
    }
    f32x4 O[2][4] = {};

    // staging: 8 threads/row, 16 rows per glds round
    const int srow = t >> 3, scb = t & 7;
    const int gcb = scb ^ (srow & 7);
    const u16* kgp = Kg + base + (size_t)srow * HDIM + gcb * 8;
    const u16* vgp = Vt + base + (size_t)srow * NSEQ + gcb * 8;
    u16* ksl = Ks + wave * 512;
    u16* vsl = Vs + wave * 512;

    // fragment offsets (swizzled)
    const int ph = (quad ^ (l15 & 7)) * 8;
    const int kb0 = l15 * 64 + ph, kb1 = l15 * 64 + (ph ^ 32);
    u16* PsW = Ps[wave];
    const int pw = l15 * 72 + quad * 4;
    const int prd = l15 * 72 + quad * 8;

    const float* mrow = masks + bh * NSEQ;

    for (int kt = 0; kt < NSEQ / 64; kt++) {
        __syncthreads();
        #pragma unroll
        for (int i = 0; i < 4; i++) glds16(kgp + i * 16 * HDIM, ksl + i * 1024);
        #pragma unroll
        for (int i = 0; i < 4; i++) glds16(vgp + (size_t)i * 16 * NSEQ, vsl + i * 1024);
        if (t < 16) *(float4*)&mks[t * 4] = *(const float4*)&mrow[kt * 64 + t * 4];
        kgp += 64 * HDIM; vgp += 64;
        __syncthreads();

        #pragma unroll
        for (int c = 0; c < 4; c++) {
            short8 ak0 = *(const short8*)&Ks[kb0 + c * 1024];
            short8 ak1 = *(const short8*)&Ks[kb1 + c * 1024];
            float4 mkv = *(const float4*)&mks[c * 16 + quad * 4];
            #pragma unroll
            for (int g = 0; g < 2; g++) {
                f32x4 S = {0.f, 0.f, 0.f, 0.f};
                S = mfma16(ak0, bq[g][0], S);   // S^T: rows=key, cols=q
                S = mfma16(ak1, bq[g][1], S);
                float p[4];
                #pragma unroll
                for (int r = 0; r < 4; r++) {
                    float mk = (r == 0) ? mkv.x : (r == 1) ? mkv.y : (r == 2) ? mkv.z : mkv.w;
                    float e = EXPB(fmaf(mk, Afac[g], Bfac));   // 2^(lam*log2e*(th-u))
                    float gate = RCP(1.0f + e);                // sigmoid
                    p[r] = EXPB(S[r] * CFOLD * gate);
                }
                lsum[g] += (p[0] + p[1]) + (p[2] + p[3]);
                *(uint2*)&PsW[g * 1152 + pw + c * 16] =
                    make_uint2(pack_bf16(p[0], p[1]), pack_bf16(p[2], p[3]));
            }
        }

        // PV: O^T[d][q] += V^T[d][k] * P[k][q]; V-frags shared by both q-groups
        #pragma unroll
        for (int kc = 0; kc < 2; kc++) {
            const int vb = kc ? kb1 : kb0;
            short8 bp0 = *(const short8*)&PsW[prd + kc * 32];
            short8 bp1 = *(const short8*)&PsW[1152 + prd + kc * 32];
            #pragma unroll
            for (int dt = 0; dt < 4; dt++) {
                short8 av = *(const short8*)&Vs[vb + dt * 1024];
                O[0][dt] = mfma16(av, bp0, O[0][dt]);
                O[1][dt] = mfma16(av, bp1, O[1][dt]);
            }
        }
    }

    #pragma unroll
    for (int g = 0; g < 2; g++) {
        float ls = lsum[g];
        ls += __shfl_xor(ls, 16);
        ls += __shfl_xor(ls, 32);
        float sc = mw / ls;
        u16* aor = AO + ((size_t)(b * NSEQ) + qrow + g * 16 + l15) * DIM + h * HDIM + quad * 4;
        #pragma unroll
        for (int dt = 0; dt < 4; dt++) {
            *(uint2*)(aor + dt * 16) = make_uint2(pack_bf16(O[g][dt][0] * sc, O[g][dt][1] * sc),
                                                  pack_bf16(O[g][dt][2] * sc, O[g][dt][3] * sc));
        }
    }
}

// ---------------- output projection GEMM (128x64 tiles) ----------------
__global__ __launch_bounds__(256) void gemm_proj(const u16* __restrict__ A,
                                                 const u16* __restrict__ BT,
                                                 const float* __restrict__ bias,
                                                 float* __restrict__ outp) {
    __shared__ __align__(16) u16 As[128 * 32];
    __shared__ __align__(16) u16 Bs[64 * 32];
    const int bm = blockIdx.y * 128, bn = blockIdx.x * 64;
    const int t = threadIdx.x;
    const int lane = t & 63, wave = t >> 6;
    const int l15 = lane & 15, quad = lane >> 4;
    const int wm = wave * 32;

    const u16* ga = A + (size_t)(bm + (t >> 2)) * DIM + (t & 3) * 8;
    const u16* gb = BT + (size_t)(bn + (t >> 2)) * DIM + (t & 3) * 8;
    u16* la = As + wave * 512;
    u16* lb = Bs + wave * 512;

    f32x4 acc[2][4] = {};
    for (int k0 = 0; k0 < DIM; k0 += 32) {
        __syncthreads();
        glds16(ga, la);
        glds16(ga + (size_t)64 * DIM, la + 2048);
        glds16(gb, lb);
        ga += 32; gb += 32;
        __syncthreads();
        short8 af[2], bf[4];
        #pragma unroll
        for (int i = 0; i < 2; i++) af[i] = *(const short8*)&As[(wm + i * 16 + l15) * 32 + quad * 8];
        #pragma unroll
        for (int j = 0; j < 4; j++) bf[j] = *(const short8*)&Bs[(j * 16 + l15) * 32 + quad * 8];
        #pragma unroll
        for (int i = 0; i < 2; i++)
            #pragma unroll
            for (int j = 0; j < 4; j++)
                acc[i][j] = mfma16(af[i], bf[j], acc[i][j]);
    }

    #pragma unroll
    for (int i = 0; i < 2; i++) {
        int mr = bm + wm + i * 16 + quad * 4;
        #pragma unroll
        for (int j = 0; j < 4; j++) {
            int ncol = bn + j * 16 + l15;
            float bb = bias[ncol];
            #pragma unroll
            for (int r = 0; r < 4; r++)
                outp[(size_t)(mr + r) * DIM + ncol] = acc[i][j][r] + bb;
        }
    }
}

// ---------------- launch ----------------
extern "C" void kernel_launch(void* const* d_in, const int* in_sizes, int n_in,
                              void* d_out, int out_size, void* d_ws, size_t ws_size,
                              hipStream_t stream) {
    const float* x            = (const float*)d_in[0];
    const float* masks        = (const float*)d_in[1];
    const float* lambda_r     = (const float*)d_in[2];
    const float* theta_r      = (const float*)d_in[3];
    const float* mask_weights = (const float*)d_in[4];
    const float* qkv_w        = (const float*)d_in[5];
    const float* qkv_b        = (const float*)d_in[6];
    const float* proj_w       = (const float*)d_in[7];
    const float* proj_b       = (const float*)d_in[8];
    float* outp = (float*)d_out;

    const size_t SZH = (size_t)NB * NH * NSEQ * HDIM;
    u16* xb    = (u16*)d_ws;
    u16* wqkvT = xb + (size_t)4096 * 768;
    u16* wprT  = wqkvT + (size_t)2304 * 768;
    u16* qg    = wprT + (size_t)768 * 768;
    u16* kg    = qg + SZH;
    u16* vtmp  = kg + SZH;
    u16* vt    = vtmp + SZH;
    u16* ao    = xb;  // xb dead after gemm_qkv

    prep<<<dim3(3072 + 1728 + 576), 256, 0, stream>>>(x, xb, qkv_w, wqkvT, proj_w, wprT);
    gemm_qkv<<<dim3(2304 / 128, 4096 / 128), 256, 0, stream>>>(xb, wqkvT, qkv_b, qg, kg, vtmp);
    vtrans<<<dim3(NSEQ / 64, NB * NH), 256, 0, stream>>>(vtmp, vt);
    attn_kernel<<<dim3(NSEQ / 64, NB * NH), 128, 0, stream>>>(qg, kg, vt, masks, lambda_r,
                                                              theta_r, mask_weights, ao);
    gemm_proj<<<dim3(768 / 64, 4096 / 128), 256, 0, stream>>>(ao, wprT, proj_b, outp);
}

// Round 4
// 202.164 us; speedup vs baseline: 1.0827x; 1.0827x over previous
//
#include <hip/hip_runtime.h>

typedef unsigned short u16;
typedef unsigned int u32;
typedef __attribute__((ext_vector_type(8))) short short8;
typedef __attribute__((ext_vector_type(4))) float f32x4;

#define NB 2
#define NSEQ 2048
#define DIM 768
#define NH 12
#define HDIM 64

#define LOG2E 1.44269504088896f
#define CFOLD 0.18033688f /* 0.125 * log2(e) */

#if defined(__has_builtin)
#if __has_builtin(__builtin_amdgcn_exp2f)
#define EXPB(x) __builtin_amdgcn_exp2f(x)
#else
#define EXPB(x) exp2f(x)
#endif
#if __has_builtin(__builtin_amdgcn_rcpf)
#define RCP(x) __builtin_amdgcn_rcpf(x)
#else
#define RCP(x) (1.0f / (x))
#endif
#else
#define EXPB(x) exp2f(x)
#define RCP(x) (1.0f / (x))
#endif

__device__ __forceinline__ u16 f2bf(float x) {
    union { float f; unsigned u; } v; v.f = x;
    unsigned r = v.u + 0x7fffu + ((v.u >> 16) & 1u);
    return (u16)(r >> 16);
}

__device__ __forceinline__ u32 pack_bf16(float a, float b) {
    union { float f; u32 u; } A, B; A.f = a; B.f = b;
    u32 ra = A.u + 0x7fffu + ((A.u >> 16) & 1u);
    u32 rb = B.u + 0x7fffu + ((B.u >> 16) & 1u);
    return __builtin_amdgcn_perm(rb, ra, 0x07060302u);
}

__device__ __forceinline__ f32x4 mfma16(short8 a, short8 b, f32x4 c) {
    return __builtin_amdgcn_mfma_f32_16x16x32_bf16(a, b, c, 0, 0, 0);
}

__device__ __forceinline__ void glds16(const u16* g, u16* l) {
    __builtin_amdgcn_global_load_lds((const __attribute__((address_space(1))) u32*)g,
                                     (__attribute__((address_space(3))) u32*)l, 16, 0, 0);
}

// ---------------- fused prep: x->bf16 cast + both weight transposes ----------------
__global__ __launch_bounds__(256) void prep(const float* __restrict__ x, u16* __restrict__ xb,
                                            const float* __restrict__ qkv_w, u16* __restrict__ wq,
                                            const float* __restrict__ proj_w, u16* __restrict__ wp) {
    const int t = threadIdx.x;
    int bid = blockIdx.x;
    if (bid < 3072) {
        int i = (bid * 256 + t) * 4;
        float4 v = *(const float4*)(x + i);
        *(uint2*)(xb + i) = make_uint2(pack_bf16(v.x, v.y), pack_bf16(v.z, v.w));
        return;
    }
    const float* in; u16* outp; int rows, cols, bx, by;
    if (bid < 3072 + 1728) {
        bid -= 3072; in = qkv_w; outp = wq; rows = 768; cols = 2304;
        bx = bid % 72; by = bid / 72;
    } else {
        bid -= 4800; in = proj_w; outp = wp; rows = 768; cols = 768;
        bx = bid % 24; by = bid / 24;
    }
    __shared__ float tile[32][33];
    int c0 = bx * 32, r0 = by * 32;
    int tx = t & 31, ty = t >> 5;
    #pragma unroll
    for (int i = 0; i < 32; i += 8)
        tile[ty + i][tx] = in[(size_t)(r0 + ty + i) * cols + c0 + tx];
    __syncthreads();
    #pragma unroll
    for (int i = 0; i < 32; i += 8)
        outp[(size_t)(c0 + ty + i) * rows + r0 + tx] = f2bf(tile[tx][ty + i]);
}

// V [bh][n][64] -> V^T [bh][64][n]
__global__ __launch_bounds__(256) void vtrans(const u16* __restrict__ vin,
                                              u16* __restrict__ vout) {
    __shared__ __align__(16) u16 tile[64][72];
    const int bh = blockIdx.y;
    const int n0 = blockIdx.x * 64;
    const int t = threadIdx.x;
    const size_t base = (size_t)bh * NSEQ * HDIM;
    int r = t >> 3, cb = (t & 7) * 8;
    *(uint4*)&tile[r][cb]      = *(const uint4*)&vin[base + (size_t)(n0 + r) * HDIM + cb];
    *(uint4*)&tile[r + 32][cb] = *(const uint4*)&vin[base + (size_t)(n0 + r + 32) * HDIM + cb];
    __syncthreads();
    #pragma unroll
    for (int half = 0; half < 2; half++) {
        int d = (t >> 3) + half * 32;
        int nb = (t & 7) * 8;
        short8 v;
        #pragma unroll
        for (int j = 0; j < 8; j++) v[j] = (short)tile[nb + j][d];
        *(short8*)&vout[base + (size_t)d * NSEQ + n0 + nb] = v;
    }
}

// ---------------- QKV GEMM: dbuf, 1 barrier/iter, swizzled LDS ----------------
__global__ __launch_bounds__(256) void gemm_qkv(const u16* __restrict__ A,
                                                const u16* __restrict__ BT,
                                                const float* __restrict__ bias,
                                                u16* __restrict__ qo,
                                                u16* __restrict__ ko,
                                                u16* __restrict__ vo) {
    __shared__ __align__(16) u16 As[2][4096];
    __shared__ __align__(16) u16 Bs[2][4096];
    const int bm = blockIdx.y * 128, bn = blockIdx.x * 128;
    const int t = threadIdx.x;
    const int lane = t & 63, wave = t >> 6;
    const int l15 = lane & 15, quad = lane >> 4;
    const int wm = (wave >> 1) * 64, wn = (wave & 1) * 64;

    // staging: row = t>>2 (0..63), 16B chunk (t&3) swizzled by (row>>1)&3
    const int srow = t >> 2;
    const int sc = (t & 3) ^ ((srow >> 1) & 3);
    const u16* ga = A + (size_t)(bm + srow) * DIM + sc * 8;
    const u16* gb = BT + (size_t)(bn + srow) * DIM + sc * 8;
    const int ldst = wave * 512;
    const int swz = (quad ^ ((l15 >> 1) & 3)) * 8;

    f32x4 acc[4][4] = {};
    glds16(ga, &As[0][ldst]); glds16(ga + (size_t)64 * DIM, &As[0][2048 + ldst]);
    glds16(gb, &Bs[0][ldst]); glds16(gb + (size_t)64 * DIM, &Bs[0][2048 + ldst]);
    ga += 32; gb += 32;

    const int NKT = DIM / 32;
    for (int kt = 0; kt < NKT; kt++) {
        const int buf = kt & 1;
        __syncthreads();
        if (kt + 1 < NKT) {
            glds16(ga, &As[buf ^ 1][ldst]); glds16(ga + (size_t)64 * DIM, &As[buf ^ 1][2048 + ldst]);
            glds16(gb, &Bs[buf ^ 1][ldst]); glds16(gb + (size_t)64 * DIM, &Bs[buf ^ 1][2048 + ldst]);
            ga += 32; gb += 32;
        }
        short8 af[4], bf[4];
        #pragma unroll
        for (int i = 0; i < 4; i++) af[i] = *(const short8*)&As[buf][(wm + i * 16 + l15) * 32 + swz];
        #pragma unroll
        for (int j = 0; j < 4; j++) bf[j] = *(const short8*)&Bs[buf][(wn + j * 16 + l15) * 32 + swz];
        #pragma unroll
        for (int i = 0; i < 4; i++)
            #pragma unroll
            for (int j = 0; j < 4; j++)
                acc[i][j] = mfma16(af[i], bf[j], acc[i][j]);
    }

    #pragma unroll
    for (int i = 0; i < 4; i++) {
        int mr = bm + wm + i * 16 + quad * 4;
        int b = mr >> 11, nn = mr & 2047;
        #pragma unroll
        for (int j = 0; j < 4; j++) {
            int ncol = bn + wn + j * 16 + l15;
            int w = ncol / DIM, rem = ncol - w * DIM;
            int h = rem >> 6, hd = rem & 63;
            u16* dst = (w == 0) ? qo : (w == 1) ? ko : vo;
            float bb = bias[ncol];
            size_t idx = (((size_t)(b * NH + h)) * NSEQ + nn) * HDIM + hd;
            #pragma unroll
            for (int r = 0; r < 4; r++)
                dst[idx + (size_t)r * HDIM] = f2bf(acc[i][j][r] + bb);
        }
    }
}

// ---------------- fused region-gated attention: 4 waves, dbuf K/V, 1 barrier/tile ----
__global__ __launch_bounds__(256) void attn_kernel(const u16* __restrict__ Q,
                                                   const u16* __restrict__ Kg,
                                                   const u16* __restrict__ Vt,
                                                   const float* __restrict__ masks,
                                                   const float* __restrict__ lambda_r,
                                                   const float* __restrict__ theta_r,
                                                   const float* __restrict__ mask_w,
                                                   u16* __restrict__ AO) {
    const int bh = blockIdx.y;
    const int b = bh / NH, h = bh % NH;
    const int qb = blockIdx.x * 64;
    const int t = threadIdx.x, wave = t >> 6, lane = t & 63;
    const int l15 = lane & 15, quad = lane >> 4;

    __shared__ __align__(16) u16 Ks[2][4096];   // [key][d], swizzled 16B chunks
    __shared__ __align__(16) u16 Vs[2][4096];   // [d][key], swizzled 16B chunks
    __shared__ __align__(16) u16 Ps[4][1152];   // per-wave P [16 q][72]
    __shared__ __align__(16) float mks[2][64];

    const float lam = lambda_r[bh], th = theta_r[bh], mw = mask_w[bh];
    const float Bfac = lam * th * LOG2E;

    const size_t base = (size_t)bh * (NSEQ * HDIM);
    const int qrow = qb + wave * 16;

    const u16* Qr = Q + base + (size_t)(qrow + l15) * HDIM;
    short8 bq0 = *(const short8*)(Qr + quad * 8);
    short8 bq1 = *(const short8*)(Qr + 32 + quad * 8);
    const float Afac = -lam * LOG2E * masks[bh * NSEQ + qrow + l15];

    // staging: 256 thr cover 32 rows x 8 chunks per site; chunk swizzled by row&7
    const int srow = t >> 3;
    const int gc = (t & 7) ^ (srow & 7);
    const u16* kgp = Kg + base + (size_t)srow * HDIM + gc * 8;
    const u16* vgp = Vt + base + (size_t)srow * NSEQ + gc * 8;
    const int ldst = wave * 512;

    const int ph = (quad ^ (l15 & 7)) * 8;
    const int kb0 = l15 * 64 + ph, kb1 = l15 * 64 + (ph ^ 32);
    u16* PsW = Ps[wave];
    const int pw = l15 * 72 + quad * 4;
    const int prd = l15 * 72 + quad * 8;
    const float* mrow = masks + bh * NSEQ;

    float lsum = 0.f;
    f32x4 O[4] = {};

    // prologue: stage tile 0 into buf 0
    glds16(kgp, &Ks[0][ldst]);
    glds16(kgp + 32 * HDIM, &Ks[0][2048 + ldst]);
    glds16(vgp, &Vs[0][ldst]);
    glds16(vgp + (size_t)32 * NSEQ, &Vs[0][2048 + ldst]);
    if (t < 16) *(float4*)&mks[0][t * 4] = *(const float4*)&mrow[t * 4];

    const int NT = NSEQ / 64;
    for (int kt = 0; kt < NT; kt++) {
        const int buf = kt & 1;
        __syncthreads();   // drains stage(kt); safe to overwrite buf^1 (readers of kt-1 done)
        if (kt + 1 < NT) {
            const u16* kn = kgp + (kt + 1) * 64 * HDIM;
            const u16* vn = vgp + (kt + 1) * 64;
            glds16(kn, &Ks[buf ^ 1][ldst]);
            glds16(kn + 32 * HDIM, &Ks[buf ^ 1][2048 + ldst]);
            glds16(vn, &Vs[buf ^ 1][ldst]);
            glds16(vn + (size_t)32 * NSEQ, &Vs[buf ^ 1][2048 + ldst]);
            if (t < 16) *(float4*)&mks[buf ^ 1][t * 4] = *(const float4*)&mrow[(kt + 1) * 64 + t * 4];
        }
        const u16* KsB = Ks[buf];
        const u16* VsB = Vs[buf];
        const float* mkb = mks[buf];

        #pragma unroll
        for (int c = 0; c < 4; c++) {
            short8 ak0 = *(const short8*)&KsB[kb0 + c * 1024];
            short8 ak1 = *(const short8*)&KsB[kb1 + c * 1024];
            f32x4 S = {0.f, 0.f, 0.f, 0.f};
            S = mfma16(ak0, bq0, S);   // S^T: rows=key, cols=q
            S = mfma16(ak1, bq1, S);
            float4 mkv = *(const float4*)&mkb[c * 16 + quad * 4];
            float p[4];
            #pragma unroll
            for (int r = 0; r < 4; r++) {
                float mk = (r == 0) ? mkv.x : (r == 1) ? mkv.y : (r == 2) ? mkv.z : mkv.w;
                float e = EXPB(fmaf(mk, Afac, Bfac));   // 2^(lam*log2e*(th-u))
                float gate = RCP(1.0f + e);             // sigmoid
                p[r] = EXPB(S[r] * CFOLD * gate);
            }
            lsum += (p[0] + p[1]) + (p[2] + p[3]);
            *(uint2*)&PsW[pw + c * 16] = make_uint2(pack_bf16(p[0], p[1]), pack_bf16(p[2], p[3]));
        }

        // PV: O^T[d][q] += V^T[d][k] * P[k][q]
        #pragma unroll
        for (int kc = 0; kc < 2; kc++) {
            const int vb = kc ? kb1 : kb0;
            short8 bp = *(const short8*)&PsW[prd + kc * 32];
            #pragma unroll
            for (int dt = 0; dt < 4; dt++) {
                short8 av = *(const short8*)&VsB[vb + dt * 1024];
                O[dt] = mfma16(av, bp, O[dt]);
            }
        }
    }

    lsum += __shfl_xor(lsum, 16);
    lsum += __shfl_xor(lsum, 32);
    float sc = mw / lsum;
    u16* aor = AO + ((size_t)(b * NSEQ) + qrow + l15) * DIM + h * HDIM + quad * 4;
    #pragma unroll
    for (int dt = 0; dt < 4; dt++) {
        *(uint2*)(aor + dt * 16) = make_uint2(pack_bf16(O[dt][0] * sc, O[dt][1] * sc),
                                              pack_bf16(O[dt][2] * sc, O[dt][3] * sc));
    }
}

// ---------------- output projection GEMM (128x64, dbuf, swizzled) ----------------
__global__ __launch_bounds__(256) void gemm_proj(const u16* __restrict__ A,
                                                 const u16* __restrict__ BT,
                                                 const float* __restrict__ bias,
                                                 float* __restrict__ outp) {
    __shared__ __align__(16) u16 As[2][4096];
    __shared__ __align__(16) u16 Bs[2][2048];
    const int bm = blockIdx.y * 128, bn = blockIdx.x * 64;
    const int t = threadIdx.x;
    const int lane = t & 63, wave = t >> 6;
    const int l15 = lane & 15, quad = lane >> 4;
    const int wm = wave * 32;

    const int srow = t >> 2;
    const int sc = (t & 3) ^ ((srow >> 1) & 3);
    const u16* ga = A + (size_t)(bm + srow) * DIM + sc * 8;
    const u16* gb = BT + (size_t)(bn + srow) * DIM + sc * 8;
    const int ldst = wave * 512;
    const int swz = (quad ^ ((l15 >> 1) & 3)) * 8;

    f32x4 acc[2][4] = {};
    glds16(ga, &As[0][ldst]); glds16(ga + (size_t)64 * DIM, &As[0][2048 + ldst]);
    glds16(gb, &Bs[0][ldst]);
    ga += 32; gb += 32;

    const int NKT = DIM / 32;
    for (int kt = 0; kt < NKT; kt++) {
        const int buf = kt & 1;
        __syncthreads();
        if (kt + 1 < NKT) {
            glds16(ga, &As[buf ^ 1][ldst]); glds16(ga + (size_t)64 * DIM, &As[buf ^ 1][2048 + ldst]);
            glds16(gb, &Bs[buf ^ 1][ldst]);
            ga += 32; gb += 32;
        }
        short8 af[2], bf[4];
        #pragma unroll
        for (int i = 0; i < 2; i++) af[i] = *(const short8*)&As[buf][(wm + i * 16 + l15) * 32 + swz];
        #pragma unroll
        for (int j = 0; j < 4; j++) bf[j] = *(const short8*)&Bs[buf][(j * 16 + l15) * 32 + swz];
        #pragma unroll
        for (int i = 0; i < 2; i++)
            #pragma unroll
            for (int j = 0; j < 4; j++)
                acc[i][j] = mfma16(af[i], bf[j], acc[i][j]);
    }

    #pragma unroll
    for (int i = 0; i < 2; i++) {
        int mr = bm + wm + i * 16 + quad * 4;
        #pragma unroll
        for (int j = 0; j < 4; j++) {
            int ncol = bn + j * 16 + l15;
            float bb = bias[ncol];
            #pragma unroll
            for (int r = 0; r < 4; r++)
                outp[(size_t)(mr + r) * DIM + ncol] = acc[i][j][r] + bb;
        }
    }
}

// ---------------- launch ----------------
extern "C" void kernel_launch(void* const* d_in, const int* in_sizes, int n_in,
                              void* d_out, int out_size, void* d_ws, size_t ws_size,
                              hipStream_t stream) {
    const float* x            = (const float*)d_in[0];
    const float* masks        = (const float*)d_in[1];
    const float* lambda_r     = (const float*)d_in[2];
    const float* theta_r      = (const float*)d_in[3];
    const float* mask_weights = (const float*)d_in[4];
    const float* qkv_w        = (const float*)d_in[5];
    const float* qkv_b        = (const float*)d_in[6];
    const float* proj_w       = (const float*)d_in[7];
    const float* proj_b       = (const float*)d_in[8];
    float* outp = (float*)d_out;

    const size_t SZH = (size_t)NB * NH * NSEQ * HDIM;
    u16* xb    = (u16*)d_ws;
    u16* wqkvT = xb + (size_t)4096 * 768;
    u16* wprT  = wqkvT + (size_t)2304 * 768;
    u16* qg    = wprT + (size_t)768 * 768;
    u16* kg    = qg + SZH;
    u16* vtmp  = kg + SZH;
    u16* vt    = vtmp + SZH;
    u16* ao    = xb;  // xb dead after gemm_qkv

    prep<<<dim3(3072 + 1728 + 576), 256, 0, stream>>>(x, xb, qkv_w, wqkvT, proj_w, wprT);
    gemm_qkv<<<dim3(2304 / 128, 4096 / 128), 256, 0, stream>>>(xb, wqkvT, qkv_b, qg, kg, vtmp);
    vtrans<<<dim3(NSEQ / 64, NB * NH), 256, 0, stream>>>(vtmp, vt);
    attn_kernel<<<dim3(NSEQ / 64, NB * NH), 256, 0, stream>>>(qg, kg, vt, masks, lambda_r,
                                                              theta_r, mask_weights, ao);
    gemm_proj<<<dim3(768 / 64, 4096 / 128), 256, 0, stream>>>(ao, wprT, proj_b, outp);
}

// Round 5
// 192.361 us; speedup vs baseline: 1.1378x; 1.0510x over previous
//
#include <hip/hip_runtime.h>

typedef unsigned short u16;
typedef unsigned int u32;
typedef __attribute__((ext_vector_type(8))) short short8;
typedef __attribute__((ext_vector_type(4))) float f32x4;

#define NB 2
#define NSEQ 2048
#define DIM 768
#define NH 12
#define HDIM 64

#define LOG2E 1.44269504088896f
#define CFOLD 0.18033688f /* 0.125 * log2(e) */

#if defined(__has_builtin)
#if __has_builtin(__builtin_amdgcn_exp2f)
#define EXPB(x) __builtin_amdgcn_exp2f(x)
#else
#define EXPB(x) exp2f(x)
#endif
#if __has_builtin(__builtin_amdgcn_rcpf)
#define RCP(x) __builtin_amdgcn_rcpf(x)
#else
#define RCP(x) (1.0f / (x))
#endif
#else
#define EXPB(x) exp2f(x)
#define RCP(x) (1.0f / (x))
#endif

__device__ __forceinline__ u16 f2bf(float x) {
    union { float f; unsigned u; } v; v.f = x;
    unsigned r = v.u + 0x7fffu + ((v.u >> 16) & 1u);
    return (u16)(r >> 16);
}

// RTNE pack (used in prep where cost is irrelevant)
__device__ __forceinline__ u32 pack_bf16(float a, float b) {
    union { float f; u32 u; } A, B; A.f = a; B.f = b;
    u32 ra = A.u + 0x7fffu + ((A.u >> 16) & 1u);
    u32 rb = B.u + 0x7fffu + ((B.u >> 16) & 1u);
    return __builtin_amdgcn_perm(rb, ra, 0x07060302u);
}

// cheap round-to-nearest pack: 2 adds + 1 perm
__device__ __forceinline__ u32 pack_rtn(float a, float b) {
    union { float f; u32 u; } A, B; A.f = a; B.f = b;
    return __builtin_amdgcn_perm(B.u + 0x8000u, A.u + 0x8000u, 0x07060302u);
}

__device__ __forceinline__ f32x4 mfma16(short8 a, short8 b, f32x4 c) {
    return __builtin_amdgcn_mfma_f32_16x16x32_bf16(a, b, c, 0, 0, 0);
}

__device__ __forceinline__ void glds16(const u16* g, u16* l) {
    __builtin_amdgcn_global_load_lds((const __attribute__((address_space(1))) u32*)g,
                                     (__attribute__((address_space(3))) u32*)l, 16, 0, 0);
}

// ---------------- fused prep: x->bf16 cast + both weight transposes ----------------
__global__ __launch_bounds__(256) void prep(const float* __restrict__ x, u16* __restrict__ xb,
                                            const float* __restrict__ qkv_w, u16* __restrict__ wq,
                                            const float* __restrict__ proj_w, u16* __restrict__ wp) {
    const int t = threadIdx.x;
    int bid = blockIdx.x;
    if (bid < 3072) {
        int i = (bid * 256 + t) * 4;
        float4 v = *(const float4*)(x + i);
        *(uint2*)(xb + i) = make_uint2(pack_bf16(v.x, v.y), pack_bf16(v.z, v.w));
        return;
    }
    const float* in; u16* outp; int rows, cols, bx, by;
    if (bid < 3072 + 1728) {
        bid -= 3072; in = qkv_w; outp = wq; rows = 768; cols = 2304;
        bx = bid % 72; by = bid / 72;
    } else {
        bid -= 4800; in = proj_w; outp = wp; rows = 768; cols = 768;
        bx = bid % 24; by = bid / 24;
    }
    __shared__ float tile[32][33];
    int c0 = bx * 32, r0 = by * 32;
    int tx = t & 31, ty = t >> 5;
    #pragma unroll
    for (int i = 0; i < 32; i += 8)
        tile[ty + i][tx] = in[(size_t)(r0 + ty + i) * cols + c0 + tx];
    __syncthreads();
    #pragma unroll
    for (int i = 0; i < 32; i += 8)
        outp[(size_t)(c0 + ty + i) * rows + r0 + tx] = f2bf(tile[tx][ty + i]);
}

// ---------------- QKV GEMM: dbuf K-loop + LDS-round-trip epilogue ----------------
// writes q,k -> [bh][n][64]; v -> V^T [bh][64][n] directly (vtrans fused here)
__global__ __launch_bounds__(256) void gemm_qkv(const u16* __restrict__ A,
                                                const u16* __restrict__ BT,
                                                const float* __restrict__ bias,
                                                u16* __restrict__ qo,
                                                u16* __restrict__ ko,
                                                u16* __restrict__ vo) {
    __shared__ __align__(16) u16 pool[17408];   // As(2x4096) Bs(2x4096) | Cs(128x136)
    const int bm = blockIdx.y * 128, bn = blockIdx.x * 128;
    const int t = threadIdx.x;
    const int lane = t & 63, wave = t >> 6;
    const int l15 = lane & 15, quad = lane >> 4;
    const int wm = (wave >> 1) * 64, wn = (wave & 1) * 64;

    const int srow = t >> 2;
    const int sc = (t & 3) ^ ((srow >> 1) & 3);
    const u16* ga = A + (size_t)(bm + srow) * DIM + sc * 8;
    const u16* gb = BT + (size_t)(bn + srow) * DIM + sc * 8;
    const int ldst = wave * 512;
    const int swz = (quad ^ ((l15 >> 1) & 3)) * 8;
    u16* As0 = pool;            // [2][4096]
    u16* Bs0 = pool + 8192;     // [2][4096]

    f32x4 acc[4][4] = {};
    glds16(ga, As0 + ldst); glds16(ga + (size_t)64 * DIM, As0 + 2048 + ldst);
    glds16(gb, Bs0 + ldst); glds16(gb + (size_t)64 * DIM, Bs0 + 2048 + ldst);
    ga += 32; gb += 32;

    const int NKT = DIM / 32;
    for (int kt = 0; kt < NKT; kt++) {
        const int bo = (kt & 1) * 4096;
        __syncthreads();
        if (kt + 1 < NKT) {
            const int bn2 = (bo ^ 4096);
            glds16(ga, As0 + bn2 + ldst); glds16(ga + (size_t)64 * DIM, As0 + bn2 + 2048 + ldst);
            glds16(gb, Bs0 + bn2 + ldst); glds16(gb + (size_t)64 * DIM, Bs0 + bn2 + 2048 + ldst);
            ga += 32; gb += 32;
        }
        short8 af[4], bf[4];
        #pragma unroll
        for (int i = 0; i < 4; i++) af[i] = *(const short8*)&As0[bo + (wm + i * 16 + l15) * 32 + swz];
        #pragma unroll
        for (int j = 0; j < 4; j++) bf[j] = *(const short8*)&Bs0[bo + (wn + j * 16 + l15) * 32 + swz];
        #pragma unroll
        for (int i = 0; i < 4; i++)
            #pragma unroll
            for (int j = 0; j < 4; j++)
                acc[i][j] = mfma16(af[i], bf[j], acc[i][j]);
    }

    // ---- epilogue: C tile -> LDS (bf16, stride 136) -> coalesced stores ----
    __syncthreads();
    u16* Cs = pool;
    #pragma unroll
    for (int i = 0; i < 4; i++) {
        int row0 = wm + i * 16 + quad * 4;
        #pragma unroll
        for (int j = 0; j < 4; j++) {
            int lcol = wn + j * 16 + l15;
            float bb = bias[bn + lcol];
            #pragma unroll
            for (int r = 0; r < 4; r++)
                Cs[(row0 + r) * 136 + lcol] = f2bf(acc[i][j][r] + bb);
        }
    }
    __syncthreads();

    const int w = bn / DIM;             // 0=Q 1=K 2=V (uniform per block)
    const int h0 = (bn - w * DIM) >> 6;
    const int b = bm >> 11, nnb = bm & 2047;
    if (w < 2) {
        u16* dst = w ? ko : qo;
        #pragma unroll
        for (int p = 0; p < 8; p++) {
            int row = p * 16 + (t >> 4);
            int chunk = t & 15;
            short8 v = *(const short8*)&Cs[row * 136 + chunk * 8];
            *(short8*)&dst[(((size_t)(b * NH + h0 + (chunk >> 3))) * NSEQ + nnb + row) * HDIM +
                           (chunk & 7) * 8] = v;
        }
    } else {
        #pragma unroll
        for (int p = 0; p < 8; p++) {
            int hdf = p * 16 + (t >> 4);
            int nn0 = (t & 15) * 8;
            short8 v;
            #pragma unroll
            for (int k = 0; k < 8; k++) v[k] = (short)Cs[(nn0 + k) * 136 + hdf];
            *(short8*)&vo[(((size_t)(b * NH + h0 + (hdf >> 6))) * HDIM + (hdf & 63)) * NSEQ +
                          nnb + nn0] = v;
        }
    }
}

// ---------------- fused region-gated attention: 4 waves, dbuf K/V, gates hoisted ----
__global__ __launch_bounds__(256) void attn_kernel(const u16* __restrict__ Q,
                                                   const u16* __restrict__ Kg,
                                                   const u16* __restrict__ Vt,
                                                   const float* __restrict__ masks,
                                                   const float* __restrict__ lambda_r,
                                                   const float* __restrict__ theta_r,
                                                   const float* __restrict__ mask_w,
                                                   u16* __restrict__ AO) {
    const int bh = blockIdx.y;
    const int b = bh / NH, h = bh % NH;
    const int qb = blockIdx.x * 64;
    const int t = threadIdx.x, wave = t >> 6, lane = t & 63;
    const int l15 = lane & 15, quad = lane >> 4;

    __shared__ __align__(16) u16 Ks[2][4096];   // [key][d], swizzled 16B chunks
    __shared__ __align__(16) u16 Vs[2][4096];   // [d][key], swizzled 16B chunks
    __shared__ __align__(16) u16 Ps[4][1152];   // per-wave P [16 q][72]
    __shared__ __align__(16) float mks[2][64];

    const float lam = lambda_r[bh], th = theta_r[bh], mw = mask_w[bh];
    const float Bfac = lam * th * LOG2E;

    const size_t base = (size_t)bh * (NSEQ * HDIM);
    const int qrow = qb + wave * 16;

    const u16* Qr = Q + base + (size_t)(qrow + l15) * HDIM;
    short8 bq0 = *(const short8*)(Qr + quad * 8);
    short8 bq1 = *(const short8*)(Qr + 32 + quad * 8);
    const float Afac = -lam * LOG2E * masks[bh * NSEQ + qrow + l15];

    const int srow = t >> 3;
    const int gc = (t & 7) ^ (srow & 7);
    const u16* kgp = Kg + base + (size_t)srow * HDIM + gc * 8;
    const u16* vgp = Vt + base + (size_t)srow * NSEQ + gc * 8;
    const int ldst = wave * 512;

    const int ph = (quad ^ (l15 & 7)) * 8;
    const int kb0 = l15 * 64 + ph, kb1 = l15 * 64 + (ph ^ 32);
    u16* PsW = Ps[wave];
    const int pw = l15 * 72 + quad * 4;
    const int prd = l15 * 72 + quad * 8;
    const float* mrow = masks + bh * NSEQ;

    float lsum = 0.f;
    f32x4 O[4] = {};

    glds16(kgp, &Ks[0][ldst]);
    glds16(kgp + 32 * HDIM, &Ks[0][2048 + ldst]);
    glds16(vgp, &Vs[0][ldst]);
    glds16(vgp + (size_t)32 * NSEQ, &Vs[0][2048 + ldst]);
    if (t < 16) *(float4*)&mks[0][t * 4] = *(const float4*)&mrow[t * 4];

    const int NT = NSEQ / 64;
    for (int kt = 0; kt < NT; kt++) {
        const int buf = kt & 1;
        __syncthreads();
        if (kt + 1 < NT) {
            const u16* kn = kgp + (kt + 1) * 64 * HDIM;
            const u16* vn = vgp + (kt + 1) * 64;
            glds16(kn, &Ks[buf ^ 1][ldst]);
            glds16(kn + 32 * HDIM, &Ks[buf ^ 1][2048 + ldst]);
            glds16(vn, &Vs[buf ^ 1][ldst]);
            glds16(vn + (size_t)32 * NSEQ, &Vs[buf ^ 1][2048 + ldst]);
            if (t < 16) *(float4*)&mks[buf ^ 1][t * 4] = *(const float4*)&mrow[(kt + 1) * 64 + t * 4];
        }
        const u16* KsB = Ks[buf];
        const u16* VsB = Vs[buf];
        const float* mkb = mks[buf];

        // hoisted gates: gp = CFOLD * sigmoid(lam*(mq*mk - th)), off the S critical path
        float gp[4][4];
        #pragma unroll
        for (int c = 0; c < 4; c++) {
            float4 mkv = *(const float4*)&mkb[c * 16 + quad * 4];
            #pragma unroll
            for (int r = 0; r < 4; r++) {
                float mk = (r == 0) ? mkv.x : (r == 1) ? mkv.y : (r == 2) ? mkv.z : mkv.w;
                float e = EXPB(fmaf(mk, Afac, Bfac));
                gp[c][r] = CFOLD * RCP(1.0f + e);
            }
        }

        #pragma unroll
        for (int c = 0; c < 4; c++) {
            short8 ak0 = *(const short8*)&KsB[kb0 + c * 1024];
            short8 ak1 = *(const short8*)&KsB[kb1 + c * 1024];
            f32x4 S = {0.f, 0.f, 0.f, 0.f};
            S = mfma16(ak0, bq0, S);   // S^T: rows=key, cols=q
            S = mfma16(ak1, bq1, S);
            float p[4];
            #pragma unroll
            for (int r = 0; r < 4; r++) p[r] = EXPB(S[r] * gp[c][r]);
            lsum += (p[0] + p[1]) + (p[2] + p[3]);
            *(uint2*)&PsW[pw + c * 16] = make_uint2(pack_rtn(p[0], p[1]), pack_rtn(p[2], p[3]));
        }

        #pragma unroll
        for (int kc = 0; kc < 2; kc++) {
            const int vb = kc ? kb1 : kb0;
            short8 bp = *(const short8*)&PsW[prd + kc * 32];
            #pragma unroll
            for (int dt = 0; dt < 4; dt++) {
                short8 av = *(const short8*)&VsB[vb + dt * 1024];
                O[dt] = mfma16(av, bp, O[dt]);
            }
        }
    }

    lsum += __shfl_xor(lsum, 16);
    lsum += __shfl_xor(lsum, 32);
    float sc = mw / lsum;
    u16* aor = AO + ((size_t)(b * NSEQ) + qrow + l15) * DIM + h * HDIM + quad * 4;
    #pragma unroll
    for (int dt = 0; dt < 4; dt++) {
        *(uint2*)(aor + dt * 16) = make_uint2(pack_rtn(O[dt][0] * sc, O[dt][1] * sc),
                                              pack_rtn(O[dt][2] * sc, O[dt][3] * sc));
    }
}

// ---------------- output projection GEMM (128x64, dbuf) ----------------
__global__ __launch_bounds__(256) void gemm_proj(const u16* __restrict__ A,
                                                 const u16* __restrict__ BT,
                                                 const float* __restrict__ bias,
                                                 float* __restrict__ outp) {
    __shared__ __align__(16) u16 As[2][4096];
    __shared__ __align__(16) u16 Bs[2][2048];
    const int bm = blockIdx.y * 128, bn = blockIdx.x * 64;
    const int t = threadIdx.x;
    const int lane = t & 63, wave = t >> 6;
    const int l15 = lane & 15, quad = lane >> 4;
    const int wm = wave * 32;

    const int srow = t >> 2;
    const int sc = (t & 3) ^ ((srow >> 1) & 3);
    const u16* ga = A + (size_t)(bm + srow) * DIM + sc * 8;
    const u16* gb = BT + (size_t)(bn + srow) * DIM + sc * 8;
    const int ldst = wave * 512;
    const int swz = (quad ^ ((l15 >> 1) & 3)) * 8;

    f32x4 acc[2][4] = {};
    glds16(ga, &As[0][ldst]); glds16(ga + (size_t)64 * DIM, &As[0][2048 + ldst]);
    glds16(gb, &Bs[0][ldst]);
    ga += 32; gb += 32;

    const int NKT = DIM / 32;
    for (int kt = 0; kt < NKT; kt++) {
        const int buf = kt & 1;
        __syncthreads();
        if (kt + 1 < NKT) {
            glds16(ga, &As[buf ^ 1][ldst]); glds16(ga + (size_t)64 * DIM, &As[buf ^ 1][2048 + ldst]);
            glds16(gb, &Bs[buf ^ 1][ldst]);
            ga += 32; gb += 32;
        }
        short8 af[2], bf[4];
        #pragma unroll
        for (int i = 0; i < 2; i++) af[i] = *(const short8*)&As[buf][(wm + i * 16 + l15) * 32 + swz];
        #pragma unroll
        for (int j = 0; j < 4; j++) bf[j] = *(const short8*)&Bs[buf][(j * 16 + l15) * 32 + swz];
        #pragma unroll
        for (int i = 0; i < 2; i++)
            #pragma unroll
            for (int j = 0; j < 4; j++)
                acc[i][j] = mfma16(af[i], bf[j], acc[i][j]);
    }

    #pragma unroll
    for (int i = 0; i < 2; i++) {
        int mr = bm + wm + i * 16 + quad * 4;
        #pragma unroll
        for (int j = 0; j < 4; j++) {
            int ncol = bn + j * 16 + l15;
            float bb = bias[ncol];
            #pragma unroll
            for (int r = 0; r < 4; r++)
                outp[(size_t)(mr + r) * DIM + ncol] = acc[i][j][r] + bb;
        }
    }
}

// ---------------- launch ----------------
extern "C" void kernel_launch(void* const* d_in, const int* in_sizes, int n_in,
                              void* d_out, int out_size, void* d_ws, size_t ws_size,
                              hipStream_t stream) {
    const float* x            = (const float*)d_in[0];
    const float* masks        = (const float*)d_in[1];
    const float* lambda_r     = (const float*)d_in[2];
    const float* theta_r      = (const float*)d_in[3];
    const float* mask_weights = (const float*)d_in[4];
    const float* qkv_w        = (const float*)d_in[5];
    const float* qkv_b        = (const float*)d_in[6];
    const float* proj_w       = (const float*)d_in[7];
    const float* proj_b       = (const float*)d_in[8];
    float* outp = (float*)d_out;

    const size_t SZH = (size_t)NB * NH * NSEQ * HDIM;
    u16* xb    = (u16*)d_ws;
    u16* wqkvT = xb + (size_t)4096 * 768;
    u16* wprT  = wqkvT + (size_t)2304 * 768;
    u16* qg    = wprT + (size_t)768 * 768;
    u16* kg    = qg + SZH;
    u16* vt    = kg + SZH;
    u16* ao    = xb;  // xb dead after gemm_qkv

    prep<<<dim3(3072 + 1728 + 576), 256, 0, stream>>>(x, xb, qkv_w, wqkvT, proj_w, wprT);
    gemm_qkv<<<dim3(2304 / 128, 4096 / 128), 256, 0, stream>>>(xb, wqkvT, qkv_b, qg, kg, vt);
    attn_kernel<<<dim3(NSEQ / 64, NB * NH), 256, 0, stream>>>(qg, kg, vt, masks, lambda_r,
                                                              theta_r, mask_weights, ao);
    gemm_proj<<<dim3(768 / 64, 4096 / 128), 256, 0, stream>>>(ao, wprT, proj_b, outp);
}

// Round 6
// 186.559 us; speedup vs baseline: 1.1732x; 1.0311x over previous
//
#include <hip/hip_runtime.h>

typedef unsigned short u16;
typedef unsigned int u32;
typedef __attribute__((ext_vector_type(8))) short short8;
typedef __attribute__((ext_vector_type(4))) float f32x4;

#define NB 2
#define NSEQ 2048
#define DIM 768
#define NH 12
#define HDIM 64

#define LOG2E 1.44269504088896f
#define CFOLD 0.18033688f /* 0.125 * log2(e) */

#if defined(__has_builtin)
#if __has_builtin(__builtin_amdgcn_exp2f)
#define EXPB(x) __builtin_amdgcn_exp2f(x)
#else
#define EXPB(x) exp2f(x)
#endif
#if __has_builtin(__builtin_amdgcn_rcpf)
#define RCP(x) __builtin_amdgcn_rcpf(x)
#else
#define RCP(x) (1.0f / (x))
#endif
#else
#define EXPB(x) exp2f(x)
#define RCP(x) (1.0f / (x))
#endif

__device__ __forceinline__ u16 f2bf(float x) {
    union { float f; unsigned u; } v; v.f = x;
    unsigned r = v.u + 0x7fffu + ((v.u >> 16) & 1u);
    return (u16)(r >> 16);
}

// RTNE pack (prep only)
__device__ __forceinline__ u32 pack_bf16(float a, float b) {
    union { float f; u32 u; } A, B; A.f = a; B.f = b;
    u32 ra = A.u + 0x7fffu + ((A.u >> 16) & 1u);
    u32 rb = B.u + 0x7fffu + ((B.u >> 16) & 1u);
    return __builtin_amdgcn_perm(rb, ra, 0x07060302u);
}

// cheap round-to-nearest pack: 2 adds + 1 perm
__device__ __forceinline__ u32 pack_rtn(float a, float b) {
    union { float f; u32 u; } A, B; A.f = a; B.f = b;
    return __builtin_amdgcn_perm(B.u + 0x8000u, A.u + 0x8000u, 0x07060302u);
}

__device__ __forceinline__ f32x4 mfma16(short8 a, short8 b, f32x4 c) {
    return __builtin_amdgcn_mfma_f32_16x16x32_bf16(a, b, c, 0, 0, 0);
}

__device__ __forceinline__ void glds16(const u16* g, u16* l) {
    __builtin_amdgcn_global_load_lds((const __attribute__((address_space(1))) u32*)g,
                                     (__attribute__((address_space(3))) u32*)l, 16, 0, 0);
}

// ---------------- fused prep: x->bf16 cast + both weight transposes ----------------
__global__ __launch_bounds__(256) void prep(const float* __restrict__ x, u16* __restrict__ xb,
                                            const float* __restrict__ qkv_w, u16* __restrict__ wq,
                                            const float* __restrict__ proj_w, u16* __restrict__ wp) {
    const int t = threadIdx.x;
    int bid = blockIdx.x;
    if (bid < 3072) {
        int i = (bid * 256 + t) * 4;
        float4 v = *(const float4*)(x + i);
        *(uint2*)(xb + i) = make_uint2(pack_bf16(v.x, v.y), pack_bf16(v.z, v.w));
        return;
    }
    const float* in; u16* outp; int rows, cols, bx, by;
    if (bid < 3072 + 1728) {
        bid -= 3072; in = qkv_w; outp = wq; rows = 768; cols = 2304;
        bx = bid % 72; by = bid / 72;
    } else {
        bid -= 4800; in = proj_w; outp = wp; rows = 768; cols = 768;
        bx = bid % 24; by = bid / 24;
    }
    __shared__ float tile[32][33];
    int c0 = bx * 32, r0 = by * 32;
    int tx = t & 31, ty = t >> 5;
    #pragma unroll
    for (int i = 0; i < 32; i += 8)
        tile[ty + i][tx] = in[(size_t)(r0 + ty + i) * cols + c0 + tx];
    __syncthreads();
    #pragma unroll
    for (int i = 0; i < 32; i += 8)
        outp[(size_t)(c0 + ty + i) * rows + r0 + tx] = f2bf(tile[tx][ty + i]);
}

// ---------------- QKV GEMM: dbuf K-loop + LDS-round-trip epilogue ----------------
__global__ __launch_bounds__(256) void gemm_qkv(const u16* __restrict__ A,
                                                const u16* __restrict__ BT,
                                                const float* __restrict__ bias,
                                                u16* __restrict__ qo,
                                                u16* __restrict__ ko,
                                                u16* __restrict__ vo) {
    __shared__ __align__(16) u16 pool[17408];   // As(2x4096) Bs(2x4096) | Cs(128x136)
    const int bm = blockIdx.y * 128, bn = blockIdx.x * 128;
    const int t = threadIdx.x;
    const int lane = t & 63, wave = t >> 6;
    const int l15 = lane & 15, quad = lane >> 4;
    const int wm = (wave >> 1) * 64, wn = (wave & 1) * 64;

    const int srow = t >> 2;
    const int sc = (t & 3) ^ ((srow >> 1) & 3);
    const u16* ga = A + (size_t)(bm + srow) * DIM + sc * 8;
    const u16* gb = BT + (size_t)(bn + srow) * DIM + sc * 8;
    const int ldst = wave * 512;
    const int swz = (quad ^ ((l15 >> 1) & 3)) * 8;
    u16* As0 = pool;            // [2][4096]
    u16* Bs0 = pool + 8192;     // [2][4096]

    f32x4 acc[4][4] = {};
    glds16(ga, As0 + ldst); glds16(ga + (size_t)64 * DIM, As0 + 2048 + ldst);
    glds16(gb, Bs0 + ldst); glds16(gb + (size_t)64 * DIM, Bs0 + 2048 + ldst);
    ga += 32; gb += 32;

    const int NKT = DIM / 32;
    for (int kt = 0; kt < NKT; kt++) {
        const int bo = (kt & 1) * 4096;
        __syncthreads();
        if (kt + 1 < NKT) {
            const int bn2 = (bo ^ 4096);
            glds16(ga, As0 + bn2 + ldst); glds16(ga + (size_t)64 * DIM, As0 + bn2 + 2048 + ldst);
            glds16(gb, Bs0 + bn2 + ldst); glds16(gb + (size_t)64 * DIM, Bs0 + bn2 + 2048 + ldst);
            ga += 32; gb += 32;
        }
        short8 af[4], bf[4];
        #pragma unroll
        for (int i = 0; i < 4; i++) af[i] = *(const short8*)&As0[bo + (wm + i * 16 + l15) * 32 + swz];
        #pragma unroll
        for (int j = 0; j < 4; j++) bf[j] = *(const short8*)&Bs0[bo + (wn + j * 16 + l15) * 32 + swz];
        #pragma unroll
        for (int i = 0; i < 4; i++)
            #pragma unroll
            for (int j = 0; j < 4; j++)
                acc[i][j] = mfma16(af[i], bf[j], acc[i][j]);
    }

    __syncthreads();
    u16* Cs = pool;
    #pragma unroll
    for (int i = 0; i < 4; i++) {
        int row0 = wm + i * 16 + quad * 4;
        #pragma unroll
        for (int j = 0; j < 4; j++) {
            int lcol = wn + j * 16 + l15;
            float bb = bias[bn + lcol];
            #pragma unroll
            for (int r = 0; r < 4; r++)
                Cs[(row0 + r) * 136 + lcol] = f2bf(acc[i][j][r] + bb);
        }
    }
    __syncthreads();

    const int w = bn / DIM;
    const int h0 = (bn - w * DIM) >> 6;
    const int b = bm >> 11, nnb = bm & 2047;
    if (w < 2) {
        u16* dst = w ? ko : qo;
        #pragma unroll
        for (int p = 0; p < 8; p++) {
            int row = p * 16 + (t >> 4);
            int chunk = t & 15;
            short8 v = *(const short8*)&Cs[row * 136 + chunk * 8];
            *(short8*)&dst[(((size_t)(b * NH + h0 + (chunk >> 3))) * NSEQ + nnb + row) * HDIM +
                           (chunk & 7) * 8] = v;
        }
    } else {
        #pragma unroll
        for (int p = 0; p < 8; p++) {
            int hdf = p * 16 + (t >> 4);
            int nn0 = (t & 15) * 8;
            short8 v;
            #pragma unroll
            for (int k = 0; k < 8; k++) v[k] = (short)Cs[(nn0 + k) * 136 + hdf];
            *(short8*)&vo[(((size_t)(b * NH + h0 + (hdf >> 6))) * HDIM + (hdf & 63)) * NSEQ +
                          nnb + nn0] = v;
        }
    }
}

// ---------------- fused region-gated attention ----------------
// 512 thr / 8 waves; 64 q rows per block; wave (g,kh): q-group g=wave>>1, key-half kh=wave&1
__global__ __launch_bounds__(512) void attn_kernel(const u16* __restrict__ Q,
                                                   const u16* __restrict__ Kg,
                                                   const u16* __restrict__ Vt,
                                                   const float* __restrict__ masks,
                                                   const float* __restrict__ lambda_r,
                                                   const float* __restrict__ theta_r,
                                                   const float* __restrict__ mask_w,
                                                   u16* __restrict__ AO) {
    const int bh = blockIdx.y;
    const int b = bh / NH, h = bh % NH;
    const int qb = blockIdx.x * 64;
    const int t = threadIdx.x, wave = t >> 6, lane = t & 63;
    const int l15 = lane & 15, quad = lane >> 4;
    const int g = wave >> 1, kh = wave & 1;

    __shared__ __align__(16) u16 pool[16384];   // Ks[2][4096] | Vs[2][4096] (also epilogue O)
    __shared__ __align__(16) u16 Ps[8][640];    // per-wave P [16 q][40]
    __shared__ __align__(16) float mks[2][64];
    __shared__ float Ls[8][16];

    const float lam = lambda_r[bh], th = theta_r[bh], mw = mask_w[bh];
    const float Bfac = lam * th * LOG2E;

    const size_t base = (size_t)bh * (NSEQ * HDIM);
    const int qrow = qb + g * 16;

    const u16* Qr = Q + base + (size_t)(qrow + l15) * HDIM;
    short8 bq0 = *(const short8*)(Qr + quad * 8);
    short8 bq1 = *(const short8*)(Qr + 32 + quad * 8);
    const float Afac = -lam * LOG2E * masks[bh * NSEQ + qrow + l15];

    // staging: 512 threads cover one 64x64 bf16 tile per glds16 (16 B each)
    const int srow = t >> 3;
    const int gc = (t & 7) ^ (srow & 7);
    const u16* kgp = Kg + base + (size_t)srow * HDIM + gc * 8;
    const u16* vgp = Vt + base + (size_t)srow * NSEQ + gc * 8;
    const int wbase = wave * 512;

    const int ph = (quad ^ (l15 & 7)) * 8;
    const int vph = kh ? (ph ^ 32) : ph;     // V frag chunk for this wave's key half
    u16* PsW = Ps[wave];
    const int pw = l15 * 40 + quad * 4;      // + c*16
    const int prd = l15 * 40 + quad * 8;
    const float* mrow = masks + bh * NSEQ;

    float lsum = 0.f;
    f32x4 O[4] = {};

    glds16(kgp, pool + wbase);
    glds16(vgp, pool + 8192 + wbase);
    if (t < 16) *(float4*)&mks[0][t * 4] = *(const float4*)&mrow[t * 4];

    const int NT = NSEQ / 64;
    for (int kt = 0; kt < NT; kt++) {
        const int bufofs = (kt & 1) * 4096;
        __syncthreads();
        if (kt + 1 < NT) {
            glds16(kgp + (kt + 1) * 64 * HDIM, pool + (bufofs ^ 4096) + wbase);
            glds16(vgp + (kt + 1) * 64, pool + 8192 + (bufofs ^ 4096) + wbase);
            if (t < 16) *(float4*)&mks[(kt + 1) & 1][t * 4] =
                *(const float4*)&mrow[(kt + 1) * 64 + t * 4];
        }
        const u16* KsB = pool + bufofs;
        const u16* VsB = pool + 8192 + bufofs;
        const float* mkb = mks[kt & 1];

        // gates for this wave's 32 keys (off the S critical path)
        float gp[2][4];
        #pragma unroll
        for (int c = 0; c < 2; c++) {
            float4 mkv = *(const float4*)&mkb[kh * 32 + c * 16 + quad * 4];
            #pragma unroll
            for (int r = 0; r < 4; r++) {
                float mk = (r == 0) ? mkv.x : (r == 1) ? mkv.y : (r == 2) ? mkv.z : mkv.w;
                float e = EXPB(fmaf(mk, Afac, Bfac));
                gp[c][r] = CFOLD * RCP(1.0f + e);
            }
        }

        #pragma unroll
        for (int c = 0; c < 2; c++) {
            const int krow = kh * 32 + c * 16 + l15;
            short8 ak0 = *(const short8*)&KsB[krow * 64 + ph];
            short8 ak1 = *(const short8*)&KsB[krow * 64 + (ph ^ 32)];
            f32x4 S = {0.f, 0.f, 0.f, 0.f};
            S = mfma16(ak0, bq0, S);   // S^T: rows=key, cols=q
            S = mfma16(ak1, bq1, S);
            float p[4];
            #pragma unroll
            for (int r = 0; r < 4; r++) p[r] = EXPB(S[r] * gp[c][r]);
            lsum += (p[0] + p[1]) + (p[2] + p[3]);
            *(uint2*)&PsW[pw + c * 16] = make_uint2(pack_rtn(p[0], p[1]), pack_rtn(p[2], p[3]));
        }

        // PV over this wave's 32 keys: O^T[d][q] += V^T[d][k] * P[k][q]
        short8 bp = *(const short8*)&PsW[prd];
        #pragma unroll
        for (int dt = 0; dt < 4; dt++) {
            short8 av = *(const short8*)&VsB[(dt * 16 + l15) * 64 + vph];
            O[dt] = mfma16(av, bp, O[dt]);
        }
    }

    // ---- combine wave pairs (kh=0 with kh=1) ----
    __syncthreads();
    float* Op = (float*)pool;                 // 8 waves x 64 lanes x 16 f32 = 32 KB
    const int slot = (wave * 64 + lane) * 16;
    #pragma unroll
    for (int dt = 0; dt < 4; dt++) *(f32x4*)&Op[slot + dt * 4] = O[dt];
    float ls = lsum;
    ls += __shfl_xor(ls, 16);
    ls += __shfl_xor(ls, 32);
    if (quad == 0) Ls[wave][l15] = ls;
    __syncthreads();
    if (kh == 0) {
        const int pslot = ((wave ^ 1) * 64 + lane) * 16;
        float sc = mw / (ls + Ls[wave ^ 1][l15]);
        u16* aor = AO + ((size_t)(b * NSEQ) + qrow + l15) * DIM + h * HDIM + quad * 4;
        #pragma unroll
        for (int dt = 0; dt < 4; dt++) {
            f32x4 oc = *(const f32x4*)&Op[pslot + dt * 4];
            float o0 = (O[dt][0] + oc[0]) * sc, o1 = (O[dt][1] + oc[1]) * sc;
            float o2 = (O[dt][2] + oc[2]) * sc, o3 = (O[dt][3] + oc[3]) * sc;
            *(uint2*)(aor + dt * 16) = make_uint2(pack_rtn(o0, o1), pack_rtn(o2, o3));
        }
    }
}

// ---------------- output projection GEMM (128x64, dbuf) ----------------
__global__ __launch_bounds__(256) void gemm_proj(const u16* __restrict__ A,
                                                 const u16* __restrict__ BT,
                                                 const float* __restrict__ bias,
                                                 float* __restrict__ outp) {
    __shared__ __align__(16) u16 As[2][4096];
    __shared__ __align__(16) u16 Bs[2][2048];
    const int bm = blockIdx.y * 128, bn = blockIdx.x * 64;
    const int t = threadIdx.x;
    const int lane = t & 63, wave = t >> 6;
    const int l15 = lane & 15, quad = lane >> 4;
    const int wm = wave * 32;

    const int srow = t >> 2;
    const int sc = (t & 3) ^ ((srow >> 1) & 3);
    const u16* ga = A + (size_t)(bm + srow) * DIM + sc * 8;
    const u16* gb = BT + (size_t)(bn + srow) * DIM + sc * 8;
    const int ldst = wave * 512;
    const int swz = (quad ^ ((l15 >> 1) & 3)) * 8;

    f32x4 acc[2][4] = {};
    glds16(ga, &As[0][ldst]); glds16(ga + (size_t)64 * DIM, &As[0][2048 + ldst]);
    glds16(gb, &Bs[0][ldst]);
    ga += 32; gb += 32;

    const int NKT = DIM / 32;
    for (int kt = 0; kt < NKT; kt++) {
        const int buf = kt & 1;
        __syncthreads();
        if (kt + 1 < NKT) {
            glds16(ga, &As[buf ^ 1][ldst]); glds16(ga + (size_t)64 * DIM, &As[buf ^ 1][2048 + ldst]);
            glds16(gb, &Bs[buf ^ 1][ldst]);
            ga += 32; gb += 32;
        }
        short8 af[2], bf[4];
        #pragma unroll
        for (int i = 0; i < 2; i++) af[i] = *(const short8*)&As[buf][(wm + i * 16 + l15) * 32 + swz];
        #pragma unroll
        for (int j = 0; j < 4; j++) bf[j] = *(const short8*)&Bs[buf][(j * 16 + l15) * 32 + swz];
        #pragma unroll
        for (int i = 0; i < 2; i++)
            #pragma unroll
            for (int j = 0; j < 4; j++)
                acc[i][j] = mfma16(af[i], bf[j], acc[i][j]);
    }

    #pragma unroll
    for (int i = 0; i < 2; i++) {
        int mr = bm + wm + i * 16 + quad * 4;
        #pragma unroll
        for (int j = 0; j < 4; j++) {
            int ncol = bn + j * 16 + l15;
            float bb = bias[ncol];
            #pragma unroll
            for (int r = 0; r < 4; r++)
                outp[(size_t)(mr + r) * DIM + ncol] = acc[i][j][r] + bb;
        }
    }
}

// ---------------- launch ----------------
extern "C" void kernel_launch(void* const* d_in, const int* in_sizes, int n_in,
                              void* d_out, int out_size, void* d_ws, size_t ws_size,
                              hipStream_t stream) {
    const float* x            = (const float*)d_in[0];
    const float* masks        = (const float*)d_in[1];
    const float* lambda_r     = (const float*)d_in[2];
    const float* theta_r      = (const float*)d_in[3];
    const float* mask_weights = (const float*)d_in[4];
    const float* qkv_w        = (const float*)d_in[5];
    const float* qkv_b        = (const float*)d_in[6];
    const float* proj_w       = (const float*)d_in[7];
    const float* proj_b       = (const float*)d_in[8];
    float* outp = (float*)d_out;

    const size_t SZH = (size_t)NB * NH * NSEQ * HDIM;
    u16* xb    = (u16*)d_ws;
    u16* wqkvT = xb + (size_t)4096 * 768;
    u16* wprT  = wqkvT + (size_t)2304 * 768;
    u16* qg    = wprT + (size_t)768 * 768;
    u16* kg    = qg + SZH;
    u16* vt    = kg + SZH;
    u16* ao    = xb;  // xb dead after gemm_qkv

    prep<<<dim3(3072 + 1728 + 576), 256, 0, stream>>>(x, xb, qkv_w, wqkvT, proj_w, wprT);
    gemm_qkv<<<dim3(2304 / 128, 4096 / 128), 256, 0, stream>>>(xb, wqkvT, qkv_b, qg, kg, vt);
    attn_kernel<<<dim3(NSEQ / 64, NB * NH), 512, 0, stream>>>(qg, kg, vt, masks, lambda_r,
                                                              theta_r, mask_weights, ao);
    gemm_proj<<<dim3(768 / 64, 4096 / 128), 256, 0, stream>>>(ao, wprT, proj_b, outp);
}